// Round 6
// baseline (163.310 us; speedup 1.0000x reference)
//
#include <hip/hip_runtime.h>
#include <hip/hip_bf16.h>

// Problem constants
#define SEQ   4096
#define DM    1024
#define NH    16
#define HD    64
#define N3    3072       // 3*DM
#define WIN   512

#define LOG2E 1.4426950408889634f

typedef __attribute__((ext_vector_type(8))) short short8;   // 8 bf16 (4 VGPRs)
typedef __attribute__((ext_vector_type(4))) short short4v;  // 4 bf16 (8B)
typedef __attribute__((ext_vector_type(4))) float float4v;  // 4 fp32 acc

__device__ __forceinline__ float bf16_bits_to_float(unsigned short u) {
  return __uint_as_float(((unsigned int)u) << 16);
}

// async 16B global->LDS (m97 path: emits global_load_lds_dwordx4)
typedef __attribute__((address_space(3))) void lds_void_t;
typedef __attribute__((address_space(1))) const void gbl_void_t;
__device__ __forceinline__ void async_copy16(void* lds_dst, const void* g_src) {
  __builtin_amdgcn_global_load_lds((gbl_void_t*)g_src, (lds_void_t*)lds_dst,
                                   16, 0, 0);
}

#define VMW(n) asm volatile("s_waitcnt vmcnt(" #n ")" ::: "memory")
#define LGKM0() asm volatile("s_waitcnt lgkmcnt(0)" ::: "memory")

__device__ __forceinline__ uint4 pack_bf16x8(float4 a, float4 b) {
  __hip_bfloat16 h[8];
  h[0] = __float2bfloat16(a.x); h[1] = __float2bfloat16(a.y);
  h[2] = __float2bfloat16(a.z); h[3] = __float2bfloat16(a.w);
  h[4] = __float2bfloat16(b.x); h[5] = __float2bfloat16(b.y);
  h[6] = __float2bfloat16(b.z); h[7] = __float2bfloat16(b.w);
  return *(const uint4*)h;
}

// ---------------------------------------------------------------------------
// Block-level dtype detection (LDS reduction): 1 = fp32 inputs, 0 = bf16.
// ---------------------------------------------------------------------------
template <int NT>
__device__ __forceinline__ int detect_fp32(const unsigned short* __restrict__ probe,
                                           float* red) {
  const int t = threadIdx.x;
  float mx = 0.0f;
#pragma unroll
  for (int p = 0; p < 8; ++p) {
    float v = bf16_bits_to_float(probe[(t * 8 + p) * 2]);
    if (v != v) v = 1e38f;
    mx = fmaxf(mx, fabsf(v));
  }
  red[t] = mx;
  __syncthreads();
  for (int s = NT / 2; s > 0; s >>= 1) {
    if (t < s) red[t] = fmaxf(red[t], red[t + s]);
    __syncthreads();
  }
  const int fl = red[0] > 100.0f ? 1 : 0;
  __syncthreads();
  return fl;
}

// Wave-level dtype detection (no LDS, no barriers). All waves read identical
// addresses -> result is block- and grid-uniform (safe to branch around
// barriers).
__device__ __forceinline__ int detect_fp32_wave(
    const unsigned short* __restrict__ probe) {
  const int lane = threadIdx.x & 63;
  float mx = 0.0f;
#pragma unroll
  for (int p = 0; p < 8; ++p) {
    float v = bf16_bits_to_float(probe[(lane * 8 + p) * 2]);
    if (v != v) v = 1e38f;
    mx = fmaxf(mx, fabsf(v));
  }
  return __any(mx > 100.0f) ? 1 : 0;
}

// ---------------------------------------------------------------------------
// Kernel 1 (ROUND 19: W-transpose ONLY; the X->bf16 pass is fused into gemm).
// 768 blocks: transpose/convert W -> WT bf16.
// ---------------------------------------------------------------------------
__global__ __launch_bounds__(256) void prep(
    const void* __restrict__ w, __hip_bfloat16* __restrict__ wt) {
  __shared__ __hip_bfloat16 tile[64][66];
  __shared__ float red[256];
  const int t = threadIdx.x;
  const int bid = blockIdx.x;
  const int fl = detect_fp32<256>((const unsigned short*)w, red);
  const int n0 = (bid % 48) * 64;
  const int k0 = (bid / 48) * 64;
  const int tx = t & 63, ty0 = t >> 6;
  if (fl) {
    const float* wf = (const float*)w;
#pragma unroll
    for (int p = 0; p < 16; ++p) {
      int row = ty0 + p * 4;
      tile[row][tx] = __float2bfloat16(wf[(k0 + row) * N3 + n0 + tx]);
    }
  } else {
    const __hip_bfloat16* wb = (const __hip_bfloat16*)w;
#pragma unroll
    for (int p = 0; p < 16; ++p) {
      int row = ty0 + p * 4;
      tile[row][tx] = wb[(k0 + row) * N3 + n0 + tx];
    }
  }
  __syncthreads();
#pragma unroll
  for (int r = 0; r < 2; ++r) {
    int oe = r * 2048 + t * 8;
    int nr = oe >> 6, kc = oe & 63;
    __hip_bfloat16 v[8];
#pragma unroll
    for (int e = 0; e < 8; ++e) v[e] = tile[kc + e][nr];
    *(uint4*)&wt[(n0 + nr) * DM + k0 + kc] = *(const uint4*)v;
  }
}

// ---------------------------------------------------------------------------
// Kernel 2 (ROUND 19): KQV = X[4096,1024] * WT^T -> bf16 [4096,3072], with
// X read DIRECTLY (fp32 or bf16) -- no xb materialization.
// Geometry unchanged from verified R17: BM=128 BN=192 BK=64, 512 blocks =
// exactly 2/CU, 8 waves (2m x 4n), T2 swizzle, counted vmcnt, setprio.
// fl=0 (bf16 input): X IS A -- identical R17 loop, A via global_load_lds.
// fl=1 (fp32 input): A path is T14 reg-staged: load 4x float4 of X for tile
// kt+2 during kt's ph0, convert+ds_write into the SAME LDS layout at kt ph1.
// Ledger (fl=1, all in-flight ops):   [issue order per ktile:
//   ph0: B(kt+1) x3 gload_lds, A(kt+2) x4 reg-loads]
//   ph0 wait vmcnt(7): confirms A(kt+1) regs (needed for ph1 ds_write);
//                      leaves B(kt+1)x3 + A(kt+2)x4.
//   ph1 wait vmcnt(4): confirms B(kt+1)x3; leaves A(kt+2)x4.
//   tails: kt=14 ph0 vmcnt(3) (no A(16) issued), kt=14 ph1 vmcnt(0),
//          kt=15 vmcnt(0) no-ops.  lgkmcnt(0) seals ds_writes pre-barrier.
// Full unroll -> all parity/guard indices compile-time (rule #20).
// ---------------------------------------------------------------------------
__global__ __launch_bounds__(512, 2) void gemm_kqv(
    const void* __restrict__ xin,            // X [4096][1024] fp32 or bf16
    const __hip_bfloat16* __restrict__ BT,   // WT [3072][1024]
    __hip_bfloat16* __restrict__ C) {        // kqv [4096][3072]
  __shared__ __align__(16) __hip_bfloat16 As[2][2][128 * 32]; // [buf][khalf] 8KB
  __shared__ __align__(16) __hip_bfloat16 Bs[2][192 * 64];    // [buf] 24KB (3 units)

  const int fl = detect_fp32_wave((const unsigned short*)xin);

  const int flat = blockIdx.y * 16 + blockIdx.x;   // 0..511
  const int swz  = (flat & 7) * 64 + (flat >> 3);  // XCD chunked, bijective
  const int m0 = (swz >> 4) * 128;                 // 32 m-tiles
  const int n0 = (swz & 15) * 192;                 // 16 n-tiles

  const int t = threadIdx.x;
  const int wave = t >> 6, lane = t & 63;
  const int wm = wave >> 2, wn = wave & 3;         // 2 x 4 wave grid
  const int l15 = lane & 15, quad = lane >> 4;

  // staging geometry (all units 8KB = 1 load/thread)
  const int arow = t >> 2;                              // 0..127
  const int acol = ((t & 3) ^ (arow & 3)) * 8;          // inverse-swizzled src col
  const int brow = t >> 3;                              // 0..63 (local in unit)
  const int bcol = ((t & 7) ^ (brow & 7)) * 8;
  const long boff0 = (long)(n0 +       brow) * DM + bcol;
  const long boff1 = (long)(n0 +  64 + brow) * DM + bcol;
  const long boff2 = (long)(n0 + 128 + brow) * DM + bcol;
  const int ldst = t * 16;

#define STAGE_B(buf, kt) do { \
    const int ko_ = (kt) * 64; \
    async_copy16((char*)Bs[buf]         + ldst, &BT[boff0 + ko_]); \
    async_copy16((char*)Bs[buf] +  8192 + ldst, &BT[boff1 + ko_]); \
    async_copy16((char*)Bs[buf] + 16384 + ldst, &BT[boff2 + ko_]); } while (0)
#define STAGE_A(buf, kt) do { \
    const int ko_ = (kt) * 64; \
    async_copy16((char*)As[buf][0] + ldst, &Ab[aoff + ko_]); \
    async_copy16((char*)As[buf][1] + ldst, &Ab[aoff + ko_ + 32]); } while (0)

  float4v acc[4][3] = {};

  if (fl) {
    // ================= fp32-input path: A reg-staged with conversion =======
    const float* ax = (const float*)xin + (long)(m0 + arow) * DM + acol;
    float4 la[2][4];

    // prologue: A(0) -> LDS directly; B(0) staged; A(1) -> la[1]
    {
      float4 r0 = *(const float4*)(ax + 0);
      float4 r1 = *(const float4*)(ax + 4);
      float4 r2 = *(const float4*)(ax + 32);
      float4 r3 = *(const float4*)(ax + 36);
      STAGE_B(0, 0);
      la[1][0] = *(const float4*)(ax + 64);
      la[1][1] = *(const float4*)(ax + 68);
      la[1][2] = *(const float4*)(ax + 96);
      la[1][3] = *(const float4*)(ax + 100);
      VMW(7);   // r0..r3 complete (B(0)x3 + A(1)x4 = 7 newer)
      *(uint4*)((char*)As[0][0] + ldst) = pack_bf16x8(r0, r1);
      *(uint4*)((char*)As[0][1] + ldst) = pack_bf16x8(r2, r3);
      VMW(4);   // B(0) complete (A(1)x4 outstanding)
      LGKM0();
      __builtin_amdgcn_s_barrier();
    }

#pragma unroll
    for (int kt = 0; kt < 16; ++kt) {
      const int P = kt & 1, N = P ^ 1;
      short8 a[4], b[3];

      // ---- ph0 ----
#pragma unroll
      for (int mi = 0; mi < 4; ++mi) {
        const int row = wm * 64 + mi * 16 + l15;
        a[mi] = *(const short8*)((const char*)As[P][0] + row * 64 +
                                 ((quad ^ (row & 3)) << 4));
      }
#pragma unroll
      for (int ni = 0; ni < 3; ++ni) {
        const int row = wn * 48 + ni * 16 + l15;
        b[ni] = *(const short8*)((const char*)Bs[P] + row * 128 +
                                 ((quad ^ (row & 7)) << 4));
      }
      if (kt < 15) STAGE_B(N, kt + 1);
      if (kt < 14) {
        const float* a2 = ax + (kt + 2) * 64;
        la[P][0] = *(const float4*)(a2 + 0);
        la[P][1] = *(const float4*)(a2 + 4);
        la[P][2] = *(const float4*)(a2 + 32);
        la[P][3] = *(const float4*)(a2 + 36);
      }
      if (kt < 14)      VMW(7);
      else if (kt == 14) VMW(3);
      else               VMW(0);
      __builtin_amdgcn_s_barrier();
      __builtin_amdgcn_s_setprio(1);
#pragma unroll
      for (int mi = 0; mi < 4; ++mi)
#pragma unroll
        for (int ni = 0; ni < 3; ++ni)
          acc[mi][ni] = __builtin_amdgcn_mfma_f32_16x16x32_bf16(
              a[mi], b[ni], acc[mi][ni], 0, 0, 0);
      __builtin_amdgcn_s_setprio(0);
      __builtin_amdgcn_s_barrier();

      // ---- ph1 ----
#pragma unroll
      for (int mi = 0; mi < 4; ++mi) {
        const int row = wm * 64 + mi * 16 + l15;
        a[mi] = *(const short8*)((const char*)As[P][1] + row * 64 +
                                 ((quad ^ (row & 3)) << 4));
      }
#pragma unroll
      for (int ni = 0; ni < 3; ++ni) {
        const int row = wn * 48 + ni * 16 + l15;
        b[ni] = *(const short8*)((const char*)Bs[P] + row * 128 +
                                 (((4 + quad) ^ (row & 7)) << 4));
      }
      if (kt < 15) {
        // write A(kt+1) (loaded at kt-1 ph0 / prologue) into As[N]
        *(uint4*)((char*)As[N][0] + ldst) = pack_bf16x8(la[N][0], la[N][1]);
        *(uint4*)((char*)As[N][1] + ldst) = pack_bf16x8(la[N][2], la[N][3]);
      }
      if (kt < 14) VMW(4);
      else         VMW(0);
      LGKM0();   // seals the ds_writes (and frag reads) before publish
      __builtin_amdgcn_s_barrier();
      __builtin_amdgcn_s_setprio(1);
#pragma unroll
      for (int mi = 0; mi < 4; ++mi)
#pragma unroll
        for (int ni = 0; ni < 3; ++ni)
          acc[mi][ni] = __builtin_amdgcn_mfma_f32_16x16x32_bf16(
              a[mi], b[ni], acc[mi][ni], 0, 0, 0);
      __builtin_amdgcn_s_setprio(0);
      __builtin_amdgcn_s_barrier();
    }
  } else {
    // ================= bf16-input path: X IS A (verified R17 loop) =========
    const __hip_bfloat16* Ab = (const __hip_bfloat16*)xin;
    const long aoff = (long)(m0 + arow) * DM + acol;

    STAGE_B(0, 0); STAGE_A(0, 0);
    asm volatile("s_waitcnt vmcnt(0)" ::: "memory");
    __builtin_amdgcn_s_barrier();

    for (int kt = 0; kt < 16; ++kt) {
      const int P = kt & 1, N = P ^ 1;
      short8 a[4], b[3];

#pragma unroll
      for (int h = 0; h < 2; ++h) {
        const char* Ap = (const char*)As[P][h];
        const char* Bp = (const char*)Bs[P];
#pragma unroll
        for (int mi = 0; mi < 4; ++mi) {
          const int row = wm * 64 + mi * 16 + l15;
          a[mi] = *(const short8*)(Ap + row * 64 + ((quad ^ (row & 3)) << 4));
        }
#pragma unroll
        for (int ni = 0; ni < 3; ++ni) {
          const int row = wn * 48 + ni * 16 + l15;
          b[ni] = *(const short8*)(Bp + row * 128 +
                                   ((((h << 2) + quad) ^ (row & 7)) << 4));
        }
        if (h == 0) {
          if (kt < 15) {
            STAGE_B(N, kt + 1);
            VMW(3);
          } else {
            VMW(0);
          }
        } else {
          if (kt < 15) STAGE_A(N, kt + 1);
          VMW(1);
        }
        __builtin_amdgcn_s_barrier();
        __builtin_amdgcn_s_setprio(1);
#pragma unroll
        for (int mi = 0; mi < 4; ++mi)
#pragma unroll
          for (int ni = 0; ni < 3; ++ni)
            acc[mi][ni] = __builtin_amdgcn_mfma_f32_16x16x32_bf16(
                a[mi], b[ni], acc[mi][ni], 0, 0, 0);
        __builtin_amdgcn_s_setprio(0);
        __builtin_amdgcn_s_barrier();
      }
    }
  }
#undef STAGE_A
#undef STAGE_B

  // ---- epilogue: C[row][col], row from quad*4+r, col from l15 ----
#pragma unroll
  for (int mi = 0; mi < 4; ++mi)
#pragma unroll
    for (int ni = 0; ni < 3; ++ni)
#pragma unroll
      for (int r = 0; r < 4; ++r) {
        int row = m0 + wm * 64 + mi * 16 + quad * 4 + r;
        int col = n0 + wn * 48 + ni * 16 + l15;
        C[row * N3 + col] = __float2bfloat16(acc[mi][ni][r]);
      }
}

// ---------------------------------------------------------------------------
// Kernel 3 (unchanged from ROUND 18): single-barrier double-buffered flash
// attention, 40KB LDS -> 4 blocks/CU, sigma(k) P/V permutation, VALU lsum.
// ---------------------------------------------------------------------------
#define SWZ(row) (((((row) ^ ((row) >> 3))) & 7) << 4)

__global__ __launch_bounds__(256, 4) void attn(
    const __hip_bfloat16* __restrict__ kqv,
    const unsigned short* __restrict__ xprobe,   // d_in[0], dtype probe only
    void* __restrict__ out) {
  __shared__ __align__(16) __hip_bfloat16 Ks[2][64 * 64];  // [k][d] swizzled, 8KB each
  __shared__ __align__(16) __hip_bfloat16 Vt[2][64 * 64];  // [d][p] swizzled, 8KB each
  __shared__ __align__(16) __hip_bfloat16 Ps[64 * 64];     // [q][p] swizzled (wave-private)

  const int fl = detect_fp32_wave(xprobe);     // no barriers, no LDS
  const int h  = blockIdx.y;
  const int bx = blockIdx.x;
  const int i0 = 64 * ((bx & 7) * 8 + (bx >> 3));
  const int t    = threadIdx.x;
  const int wave = t >> 6, lane = t & 63;
  const int l15 = lane & 15, quad = lane >> 4;
  const float nslope2 = -exp2f(-0.5f * (float)(h + 1)) * LOG2E; // bias = nslope2*(i-j)
  const float qscale  = LOG2E / 32.0f;

  // Q fragments direct to registers: A[m=l15][k=quad*8+j], rows wave*16+l15
  short8 aq[2];
#pragma unroll
  for (int ks2 = 0; ks2 < 2; ++ks2)
    aq[ks2] = *(const short8*)&kqv[(i0 + wave * 16 + l15) * N3 + DM + h * HD +
                                   ks2 * 32 + quad * 8];

  float4v o[4] = {};              // o[dt][r]: row quad*4+r, col dt*16+l15
  float lsum[4] = {0.f, 0.f, 0.f, 0.f};

  const int jlo  = max(0, i0 - WIN);       // 64-aligned
  const int nblk = (i0 + 64 - jlo) >> 6;   // <= 9

  // ---- staging geometry ----
  const int krow0 = t >> 3, krow1 = (t >> 3) + 32, kd0 = (t & 7) * 8;
  const int kdst0 = krow0 * 128 + ((kd0 * 2) ^ SWZ(krow0));
  const int kdst1 = krow1 * 128 + ((kd0 * 2) ^ SWZ(krow1));
  const int rbase = t >> 3;                              // 0..31
  const int vd0   = (t & 7) * 8;
  const int kA    = (rbase & 15) + ((rbase >> 4) << 5);  // {0..15, 32..47}
  const int vsig2 = ((rbase & 15) * 8) + ((rbase >> 4) * 4); // byte col of 2*sigma(kA)

  uint4 kregA, kregB, vregA, vregB;
  // load block 0
  kregA = *(const uint4*)&kqv[(jlo + krow0) * N3 + h * HD + kd0];
  kregB = *(const uint4*)&kqv[(jlo + krow1) * N3 + h * HD + kd0];
  vregA = *(const uint4*)&kqv[(jlo + kA) * N3 + 2 * DM + h * HD + vd0];
  vregB = *(const uint4*)&kqv[(jlo + kA + 16) * N3 + 2 * DM + h * HD + vd0];

  // write buf 0
  {
    *(uint4*)((char*)Ks[0] + kdst0) = kregA;
    *(uint4*)((char*)Ks[0] + kdst1) = kregB;
    const unsigned short* pa = (const unsigned short*)&vregA;
    const unsigned short* pb = (const unsigned short*)&vregB;
#pragma unroll
    for (int e = 0; e < 8; ++e) {
      unsigned int pack = (unsigned int)pa[e] | ((unsigned int)pb[e] << 16);
      *(unsigned int*)((char*)Vt[0] + (vd0 + e) * 128 + (vsig2 ^ SWZ(vd0 + e))) = pack;
    }
  }
  // prefetch block 1
  if (nblk > 1) {
    const int jn = jlo + 64;
    kregA = *(const uint4*)&kqv[(jn + krow0) * N3 + h * HD + kd0];
    kregB = *(const uint4*)&kqv[(jn + krow1) * N3 + h * HD + kd0];
    vregA = *(const uint4*)&kqv[(jn + kA) * N3 + 2 * DM + h * HD + vd0];
    vregB = *(const uint4*)&kqv[(jn + kA + 16) * N3 + 2 * DM + h * HD + vd0];
  }
  __syncthreads();   // buf0 sealed

  for (int b = 0; b < nblk; ++b) {
    const int cur = b & 1, nxt = cur ^ 1;

    // ---- S = Q*K^T : 4 n-tiles x 2 k-steps (reads Ks[cur]) ----
    float4v sacc[4] = {};
#pragma unroll
    for (int ks2 = 0; ks2 < 2; ++ks2)
#pragma unroll
      for (int nt = 0; nt < 4; ++nt) {
        const int row = nt * 16 + l15;
        short8 bk = *(const short8*)((const char*)Ks[cur] + row * 128 +
                                     ((ks2 * 64 + quad * 16) ^ SWZ(row)));
        sacc[nt] = __builtin_amdgcn_mfma_f32_16x16x32_bf16(aq[ks2], bk, sacc[nt], 0, 0, 0);
      }

    // ---- fixed-max softmax: p = exp2(x), masked -> 0; accumulate lsum ----
    const int dbase = (i0 + wave * 16 + quad * 4) - (jlo + b * 64 + l15);
    const float s16 = nslope2 * -16.0f;   // bias step per nt
#pragma unroll
    for (int r = 0; r < 4; ++r) {
      float bias = nslope2 * (float)(dbase + r);
      int rel = dbase + r;
      short4v pk;
      float ls = 0.0f;
#pragma unroll
      for (int nt = 0; nt < 4; ++nt) {
        float x = fmaf(sacc[nt][r], qscale, bias);
        x = ((unsigned)rel <= (unsigned)WIN) ? x : -200.0f;  // exp2(-200)==0
        __hip_bfloat16 hb = __float2bfloat16(exp2f(x));
        unsigned short bits = *reinterpret_cast<const unsigned short*>(&hb);
        pk[nt] = (short)bits;
        ls += bf16_bits_to_float(bits);   // denominator from SAME rounded P
        bias += s16;
        rel -= 16;
      }
      lsum[r] += ls;
      const int prow = wave * 16 + quad * 4 + r;
      *(short4v*)((char*)Ps + prow * 128 + ((l15 * 8) ^ SWZ(prow))) = pk;
    }
    // no barrier: Ps strip is wave-private (within-wave LDS ordering via lgkmcnt)

    // ---- write NEXT buffer (data prefetched in iter b-1), then prefetch b+2.
    if (b + 1 < nblk) {
      *(uint4*)((char*)Ks[nxt] + kdst0) = kregA;
      *(uint4*)((char*)Ks[nxt] + kdst1) = kregB;
      const unsigned short* pa = (const unsigned short*)&vregA;
      const unsigned short* pb = (const unsigned short*)&vregB;
#pragma unroll
      for (int e = 0; e < 8; ++e) {
        unsigned int pack = (unsigned int)pa[e] | ((unsigned int)pb[e] << 16);
        *(unsigned int*)((char*)Vt[nxt] + (vd0 + e) * 128 + (vsig2 ^ SWZ(vd0 + e))) = pack;
      }
      if (b + 2 < nblk) {
        const int jn = jlo + (b + 2) * 64;
        kregA = *(const uint4*)&kqv[(jn + krow0) * N3 + h * HD + kd0];
        kregB = *(const uint4*)&kqv[(jn + krow1) * N3 + h * HD + kd0];
        vregA = *(const uint4*)&kqv[(jn + kA) * N3 + 2 * DM + h * HD + vd0];
        vregB = *(const uint4*)&kqv[(jn + kA + 16) * N3 + 2 * DM + h * HD + vd0];
      }
    }

    // ---- O += P*V (dt 0..3), reads Vt[cur] + Ps ----
#pragma unroll
    for (int ks = 0; ks < 64; ks += 32) {
      const int prow = wave * 16 + l15;
      short8 ap = *(const short8*)((const char*)Ps + prow * 128 +
                                   ((ks * 2 + quad * 16) ^ SWZ(prow)));
#pragma unroll
      for (int dt = 0; dt < 4; ++dt) {
        const int vrow = dt * 16 + l15;
        short8 bv = *(const short8*)((const char*)Vt[cur] + vrow * 128 +
                                     ((ks * 2 + quad * 16) ^ SWZ(vrow)));
        o[dt] = __builtin_amdgcn_mfma_f32_16x16x32_bf16(ap, bv, o[dt], 0, 0, 0);
      }
    }

    __syncthreads();   // seals buf nxt for iter b+1; all readers of cur done
  }

  // ---- epilogue: l = shfl-reduce of lsum over the 16-lane l15 group ----
#pragma unroll
  for (int r = 0; r < 4; ++r) {
    float s = lsum[r];
    s += __shfl_xor(s, 1, 64);
    s += __shfl_xor(s, 2, 64);
    s += __shfl_xor(s, 4, 64);
    s += __shfl_xor(s, 8, 64);
    const float inv_l = 1.0f / s;    // diagonal key j=i always valid -> s > 0
    const int row = i0 + wave * 16 + quad * 4 + r;
#pragma unroll
    for (int dt = 0; dt < 4; ++dt) {
      const int idx = row * DM + h * HD + dt * 16 + l15;
      const float v = o[dt][r] * inv_l;
      if (fl) ((float*)out)[idx] = v;
      else    ((__hip_bfloat16*)out)[idx] = __float2bfloat16(v);
    }
  }
}

// ---------------------------------------------------------------------------
extern "C" void kernel_launch(void* const* d_in, const int* in_sizes, int n_in,
                              void* d_out, int out_size, void* d_ws, size_t ws_size,
                              hipStream_t stream) {
  char* ws = (char*)d_ws;
  __hip_bfloat16* wt  = (__hip_bfloat16*)(ws + 4096);          // 6 MB
  __hip_bfloat16* kqv = (__hip_bfloat16*)(ws + 4096 + 6291456);// 24 MB

  hipLaunchKernelGGL(prep, dim3(768), dim3(256), 0, stream, d_in[1], wt);
  hipLaunchKernelGGL(gemm_kqv, dim3(16, 32), dim3(512), 0, stream,
                     d_in[0], wt, kqv);
  hipLaunchKernelGGL(attn, dim3(64, 16), dim3(256), 0, stream,
                     kqv, (const unsigned short*)d_in[0], d_out);
}

// Round 7
// 141.935 us; speedup vs baseline: 1.1506x; 1.1506x over previous
//
#include <hip/hip_runtime.h>
#include <hip/hip_bf16.h>

// Problem constants
#define SEQ   4096
#define DM    1024
#define NH    16
#define HD    64
#define N3    3072       // 3*DM
#define WIN   512

#define LOG2E 1.4426950408889634f

typedef __attribute__((ext_vector_type(8))) short short8;   // 8 bf16 (4 VGPRs)
typedef __attribute__((ext_vector_type(4))) short short4v;  // 4 bf16 (8B)
typedef __attribute__((ext_vector_type(4))) float float4v;  // 4 fp32 acc

__device__ __forceinline__ float bf16_bits_to_float(unsigned short u) {
  return __uint_as_float(((unsigned int)u) << 16);
}

// async 16B global->LDS (m97 path: emits global_load_lds_dwordx4)
typedef __attribute__((address_space(3))) void lds_void_t;
typedef __attribute__((address_space(1))) const void gbl_void_t;
__device__ __forceinline__ void async_copy16(void* lds_dst, const void* g_src) {
  __builtin_amdgcn_global_load_lds((gbl_void_t*)g_src, (lds_void_t*)lds_dst,
                                   16, 0, 0);
}

// ---------------------------------------------------------------------------
// Block-level dtype detection (LDS reduction): 1 = fp32 inputs, 0 = bf16.
// ---------------------------------------------------------------------------
template <int NT>
__device__ __forceinline__ int detect_fp32(const unsigned short* __restrict__ probe,
                                           float* red) {
  const int t = threadIdx.x;
  float mx = 0.0f;
#pragma unroll
  for (int p = 0; p < 8; ++p) {
    float v = bf16_bits_to_float(probe[(t * 8 + p) * 2]);
    if (v != v) v = 1e38f;
    mx = fmaxf(mx, fabsf(v));
  }
  red[t] = mx;
  __syncthreads();
  for (int s = NT / 2; s > 0; s >>= 1) {
    if (t < s) red[t] = fmaxf(red[t], red[t + s]);
    __syncthreads();
  }
  const int fl = red[0] > 100.0f ? 1 : 0;
  __syncthreads();
  return fl;
}

// Wave-level dtype detection (no LDS, no barriers).
__device__ __forceinline__ int detect_fp32_wave(
    const unsigned short* __restrict__ probe) {
  const int lane = threadIdx.x & 63;
  float mx = 0.0f;
#pragma unroll
  for (int p = 0; p < 8; ++p) {
    float v = bf16_bits_to_float(probe[(lane * 8 + p) * 2]);
    if (v != v) v = 1e38f;
    mx = fmaxf(mx, fabsf(v));
  }
  return __any(mx > 100.0f) ? 1 : 0;
}

// ---------------------------------------------------------------------------
// Kernel 1 (merged prep, R4-verified): blocks [0,2048) convert X -> xb bf16;
// blocks [2048, 2816) transpose/convert W -> WT bf16.
// R6 lesson: fusing the X pass into gemm costs 40us of gemm latency stall;
// the 8MB xb materialization is cheap insurance.
// ---------------------------------------------------------------------------
__global__ __launch_bounds__(256) void prep(
    const void* __restrict__ x, const void* __restrict__ w,
    __hip_bfloat16* __restrict__ xb, __hip_bfloat16* __restrict__ wt) {
  __shared__ __hip_bfloat16 tile[64][66];
  __shared__ float red[256];
  const int t = threadIdx.x;
  if (blockIdx.x < 2048) {
    const int fl = detect_fp32<256>((const unsigned short*)x, red);
    const int i0 = (blockIdx.x * 256 + t) * 8;
    if (fl) {
      const float* xf = (const float*)x + i0;
      float4 f0 = *(const float4*)(xf);
      float4 f1 = *(const float4*)(xf + 4);
      __hip_bfloat16 tmp[8];
      tmp[0] = __float2bfloat16(f0.x); tmp[1] = __float2bfloat16(f0.y);
      tmp[2] = __float2bfloat16(f0.z); tmp[3] = __float2bfloat16(f0.w);
      tmp[4] = __float2bfloat16(f1.x); tmp[5] = __float2bfloat16(f1.y);
      tmp[6] = __float2bfloat16(f1.z); tmp[7] = __float2bfloat16(f1.w);
      *(uint4*)&xb[i0] = *(const uint4*)tmp;
    } else {
      *(uint4*)&xb[i0] = *(const uint4*)((const __hip_bfloat16*)x + i0);
    }
  } else {
    const int bid = blockIdx.x - 2048;
    const int fl = detect_fp32<256>((const unsigned short*)w, red);
    const int n0 = (bid % 48) * 64;
    const int k0 = (bid / 48) * 64;
    const int tx = t & 63, ty0 = t >> 6;
    if (fl) {
      const float* wf = (const float*)w;
#pragma unroll
      for (int p = 0; p < 16; ++p) {
        int row = ty0 + p * 4;
        tile[row][tx] = __float2bfloat16(wf[(k0 + row) * N3 + n0 + tx]);
      }
    } else {
      const __hip_bfloat16* wb = (const __hip_bfloat16*)w;
#pragma unroll
      for (int p = 0; p < 16; ++p) {
        int row = ty0 + p * 4;
        tile[row][tx] = wb[(k0 + row) * N3 + n0 + tx];
      }
    }
    __syncthreads();
#pragma unroll
    for (int r = 0; r < 2; ++r) {
      int oe = r * 2048 + t * 8;
      int nr = oe >> 6, kc = oe & 63;
      __hip_bfloat16 v[8];
#pragma unroll
      for (int e = 0; e < 8; ++e) v[e] = tile[kc + e][nr];
      *(uint4*)&wt[(n0 + nr) * DM + k0 + kc] = *(const uint4*)v;
    }
  }
}

// ---------------------------------------------------------------------------
// Kernel 2 (ROUND 20 = verified R17 + A-swizzle fix):
// KQV = xb[4096,1024] * WT^T -> bf16 [4096,3072].
// T2+T3+T4+T5, BM=128 BN=192 BK=64, 512 blocks = exactly 2/CU.
// A-swizzle CHANGE vs R17: slot term (row&3) -> ((row>>1)&3). R6's PMC
// showed 2.1M SQ_LDS_BANK_CONFLICT; with (row&3), the 16 l15-lanes split
// into 2 bank phases (64B rows) and row&3 gives only 2 slot values per
// phase -> 4-way conflict. (row>>1)&3 spans all 4 slots per phase ->
// 2-way = free (m136). Applied on BOTH sides (inverse-swizzled global
// source col + swizzled ds_read), rule #21.
// ---------------------------------------------------------------------------
__global__ __launch_bounds__(512, 2) void gemm_kqv(
    const __hip_bfloat16* __restrict__ A,    // xb [4096][1024]
    const __hip_bfloat16* __restrict__ BT,   // WT [3072][1024]
    __hip_bfloat16* __restrict__ C) {        // kqv [4096][3072]
  __shared__ __align__(16) __hip_bfloat16 As[2][2][128 * 32]; // [buf][khalf] 8KB
  __shared__ __align__(16) __hip_bfloat16 Bs[2][192 * 64];    // [buf] 24KB (3 units)

  const int flat = blockIdx.y * 16 + blockIdx.x;   // 0..511
  const int swz  = (flat & 7) * 64 + (flat >> 3);  // XCD chunked, bijective
  const int m0 = (swz >> 4) * 128;                 // 32 m-tiles
  const int n0 = (swz & 15) * 192;                 // 16 n-tiles

  const int t = threadIdx.x;
  const int wave = t >> 6, lane = t & 63;
  const int wm = wave >> 2, wn = wave & 3;         // 2 x 4 wave grid
  const int l15 = lane & 15, quad = lane >> 4;

  // staging geometry (all units 8KB = 1 load/thread)
  const int arow = t >> 2;                              // 0..127
  const int acol = ((t & 3) ^ ((arow >> 1) & 3)) * 8;   // inverse-swizzled src col
  const long aoff = (long)(m0 + arow) * DM + acol;
  const int brow = t >> 3;                              // 0..63 (local in unit)
  const int bcol = ((t & 7) ^ (brow & 7)) * 8;
  const long boff0 = (long)(n0 +       brow) * DM + bcol;
  const long boff1 = (long)(n0 +  64 + brow) * DM + bcol;
  const long boff2 = (long)(n0 + 128 + brow) * DM + bcol;
  const int ldst = t * 16;

#define STAGE_B(buf, kt) do { \
    const int ko_ = (kt) * 64; \
    async_copy16((char*)Bs[buf]         + ldst, &BT[boff0 + ko_]); \
    async_copy16((char*)Bs[buf] +  8192 + ldst, &BT[boff1 + ko_]); \
    async_copy16((char*)Bs[buf] + 16384 + ldst, &BT[boff2 + ko_]); } while (0)
#define STAGE_A(buf, kt) do { \
    const int ko_ = (kt) * 64; \
    async_copy16((char*)As[buf][0] + ldst, &A[aoff + ko_]); \
    async_copy16((char*)As[buf][1] + ldst, &A[aoff + ko_ + 32]); } while (0)

  float4v acc[4][3] = {};

  // prologue: tile 0 fully staged + drained
  STAGE_B(0, 0); STAGE_A(0, 0);
  asm volatile("s_waitcnt vmcnt(0)" ::: "memory");
  __builtin_amdgcn_s_barrier();

  for (int kt = 0; kt < 16; ++kt) {
    const int P = kt & 1, N = P ^ 1;
    short8 a[4], b[3];

#pragma unroll
    for (int h = 0; h < 2; ++h) {
      const char* Ap = (const char*)As[P][h];
      const char* Bp = (const char*)Bs[P];
      // ds_read current phase's fragments (swizzled cols)
#pragma unroll
      for (int mi = 0; mi < 4; ++mi) {
        const int row = wm * 64 + mi * 16 + l15;
        a[mi] = *(const short8*)(Ap + row * 64 + ((quad ^ ((row >> 1) & 3)) << 4));
      }
#pragma unroll
      for (int ni = 0; ni < 3; ++ni) {
        const int row = wn * 48 + ni * 16 + l15;
        b[ni] = *(const short8*)(Bp + row * 128 +
                                 ((((h << 2) + quad) ^ (row & 7)) << 4));
      }
      // stage next tile's units + counted wait
      if (h == 0) {
        if (kt < 15) {
          STAGE_B(N, kt + 1);
          asm volatile("s_waitcnt vmcnt(3)" ::: "memory");
        } else {
          asm volatile("s_waitcnt vmcnt(0)" ::: "memory");
        }
      } else {
        if (kt < 15) STAGE_A(N, kt + 1);
        asm volatile("s_waitcnt vmcnt(1)" ::: "memory");
      }
      __builtin_amdgcn_s_barrier();
      __builtin_amdgcn_s_setprio(1);
#pragma unroll
      for (int mi = 0; mi < 4; ++mi)
#pragma unroll
        for (int ni = 0; ni < 3; ++ni)
          acc[mi][ni] = __builtin_amdgcn_mfma_f32_16x16x32_bf16(
              a[mi], b[ni], acc[mi][ni], 0, 0, 0);
      __builtin_amdgcn_s_setprio(0);
      __builtin_amdgcn_s_barrier();
    }
  }
#undef STAGE_A
#undef STAGE_B

  // ---- epilogue: C[row][col], row from quad*4+r, col from l15 ----
#pragma unroll
  for (int mi = 0; mi < 4; ++mi)
#pragma unroll
    for (int ni = 0; ni < 3; ++ni)
#pragma unroll
      for (int r = 0; r < 4; ++r) {
        int row = m0 + wm * 64 + mi * 16 + quad * 4 + r;
        int col = n0 + wn * 48 + ni * 16 + l15;
        C[row * N3 + col] = __float2bfloat16(acc[mi][ni][r]);
      }
}

// ---------------------------------------------------------------------------
// Kernel 3: MFMA flash attention, fixed-max softmax (m=0).
// R4-verified (141.7us total): sigma(k) permutation on P/V, swizzled Vt,
// b64 softmax stores, b128 V reads. 64-q tiles / 256 thr / single-buffer
// LDS / 4 blocks/CU / register prefetch issued after the second barrier.
// ---------------------------------------------------------------------------
__global__ __launch_bounds__(256, 4) void attn(
    const __hip_bfloat16* __restrict__ kqv,
    const unsigned short* __restrict__ xprobe,   // d_in[0], dtype probe only
    void* __restrict__ out) {
  __shared__ __align__(16) __hip_bfloat16 Ks[64 * 72];  // [k][d]
  __shared__ __align__(16) __hip_bfloat16 Vt[80 * 72];  // [d][p]; row 64 ones, 65..79 zero
  __shared__ __align__(16) __hip_bfloat16 Ps[64 * 72];  // [q][p] (wave-private strips)

  const int fl = detect_fp32_wave(xprobe);     // no barriers, no LDS
  const int h  = blockIdx.y;
  const int bx = blockIdx.x;
  const int i0 = 64 * ((bx & 7) * 8 + (bx >> 3));
  const int t    = threadIdx.x;
  const int wave = t >> 6, lane = t & 63;
  const int l15 = lane & 15, quad = lane >> 4;
  const float nslope2 = -exp2f(-0.5f * (float)(h + 1)) * LOG2E; // bias = nslope2*(i-j)
  const float qscale  = LOG2E / 32.0f;

  // ones/zero rows of Vt: row-uniform content, swizzle-invariant: write linear.
  for (int idx = t; idx < 16 * 64; idx += 256) {
    int rr = idx >> 6, cc = idx & 63;
    ((unsigned short*)Vt)[(64 + rr) * 72 + cc] = (rr == 0) ? 0x3F80 : 0;
  }

  // Q fragments direct to registers: A[m=l15][k=quad*8+j], rows wave*16+l15
  short8 aq[2];
#pragma unroll
  for (int ks2 = 0; ks2 < 2; ++ks2)
    aq[ks2] = *(const short8*)&kqv[(i0 + wave * 16 + l15) * N3 + DM + h * HD +
                                   ks2 * 32 + quad * 8];

  float4v o[5] = {};   // o[dt][r]: row quad*4+r, col dt*16+l15; dt=4 is l-column

  const int jlo  = max(0, i0 - WIN);       // 64-aligned
  const int nblk = (i0 + 64 - jlo) >> 6;   // <= 9

  // ---- staging geometry + prefetch of block 0 ----
  const int krow0 = t >> 3, krow1 = (t >> 3) + 32, kd0 = (t & 7) * 8;
  const int rbase = t >> 3;                              // 0..31
  const int vd0   = (t & 7) * 8;
  const int kA    = (rbase & 15) + ((rbase >> 4) << 5);  // {0..15, 32..47}
  const int vsig2 = (((rbase & 15) << 2) + ((rbase >> 4) << 1)) * 2; // byte pos of sigma(kA)
  const int vswz  = (t & 7) << 4;  // = ((row>>3)&7)<<4 for rows vd0..vd0+7
  uint4 kregA, kregB, vregA, vregB;
  kregA = *(const uint4*)&kqv[(jlo + krow0) * N3 + h * HD + kd0];
  kregB = *(const uint4*)&kqv[(jlo + krow1) * N3 + h * HD + kd0];
  vregA = *(const uint4*)&kqv[(jlo + kA) * N3 + 2 * DM + h * HD + vd0];
  vregB = *(const uint4*)&kqv[(jlo + kA + 16) * N3 + 2 * DM + h * HD + vd0];

  for (int b = 0; b < nblk; ++b) {
    const int j0 = jlo + b * 64;
    __syncthreads();   // prev iter's K/V readers done before overwrite
    // ---- LDS fill from prefetched registers ----
    *(uint4*)&Ks[krow0 * 72 + kd0] = kregA;
    *(uint4*)&Ks[krow1 * 72 + kd0] = kregB;
    {
      const unsigned short* pa = (const unsigned short*)&vregA;
      const unsigned short* pb = (const unsigned short*)&vregB;
      char* vbase = (char*)Vt;
#pragma unroll
      for (int e = 0; e < 8; ++e) {
        unsigned int pack = (unsigned int)pa[e] | ((unsigned int)pb[e] << 16);
        *(unsigned int*)(vbase + (vd0 + e) * 144 + (vsig2 ^ vswz)) = pack;
      }
    }
    __syncthreads();   // nothing outstanding here: prefetch not yet issued

    // ---- issue next block's prefetch NOW (covered by compute below) ----
    if (b + 1 < nblk) {
      const int jn = j0 + 64;
      kregA = *(const uint4*)&kqv[(jn + krow0) * N3 + h * HD + kd0];
      kregB = *(const uint4*)&kqv[(jn + krow1) * N3 + h * HD + kd0];
      vregA = *(const uint4*)&kqv[(jn + kA) * N3 + 2 * DM + h * HD + vd0];
      vregB = *(const uint4*)&kqv[(jn + kA + 16) * N3 + 2 * DM + h * HD + vd0];
    }

    // ---- S = Q*K^T : 4 n-tiles x 2 k-steps ----
    float4v sacc[4] = {};
#pragma unroll
    for (int ks2 = 0; ks2 < 2; ++ks2)
#pragma unroll
      for (int nt = 0; nt < 4; ++nt) {
        short8 bk = *(const short8*)&Ks[(nt * 16 + l15) * 72 + ks2 * 32 + quad * 8];
        sacc[nt] = __builtin_amdgcn_mfma_f32_16x16x32_bf16(aq[ks2], bk, sacc[nt], 0, 0, 0);
      }

    // ---- fixed-max softmax: p = exp2(x), masked -> 0 ----
    // Lane computes S[q][k = nt*16+l15]; stored at p = sigma(k) = l15*4 + nt.
    const int dbase = (i0 + wave * 16 + quad * 4) - (j0 + l15);
    const float s16 = nslope2 * -16.0f;   // bias step per nt
    const int psbase = (wave * 16 + quad * 4) * 72 + l15 * 4;
#pragma unroll
    for (int r = 0; r < 4; ++r) {
      float bias = nslope2 * (float)(dbase + r);
      int rel = dbase + r;
      short4v pk;
#pragma unroll
      for (int nt = 0; nt < 4; ++nt) {
        float x = fmaf(sacc[nt][r], qscale, bias);
        x = ((unsigned)rel <= (unsigned)WIN) ? x : -200.0f;  // exp2(-200)==0
        __hip_bfloat16 hb = __float2bfloat16(exp2f(x));
        pk[nt] = *reinterpret_cast<const short*>(&hb);
        bias += s16;
        rel -= 16;
      }
      *(short4v*)&Ps[psbase + r * 72] = pk;
    }
    // no barrier: Ps strip is wave-private

    // ---- O += P*V (dt 0..3) ; l += P*1 (dt 4, ones-row of Vt) ----
#pragma unroll
    for (int ks = 0; ks < 64; ks += 32) {
      short8 ap = *(const short8*)&Ps[(wave * 16 + l15) * 72 + ks + quad * 8];
#pragma unroll
      for (int dt = 0; dt < 5; ++dt) {
        const int vrow = dt * 16 + l15;
        const short8 bv = *(const short8*)((const char*)Vt + vrow * 144 +
            ((ks * 2 + (quad << 4)) ^ (((vrow >> 3) & 7) << 4)));
        o[dt] = __builtin_amdgcn_mfma_f32_16x16x32_bf16(ap, bv, o[dt], 0, 0, 0);
      }
    }
  }

  // ---- epilogue: l lives in o[4] col 0 (lane l15==0 of each quad group) ----
#pragma unroll
  for (int r = 0; r < 4; ++r) {
    const float l = __shfl(o[4][r], quad * 16, 64);   // broadcast from l15==0 lane
    const float inv_l = 1.0f / l;    // l >= 2^-2: diagonal key j=i always valid
    const int row = i0 + wave * 16 + quad * 4 + r;
#pragma unroll
    for (int dt = 0; dt < 4; ++dt) {
      const int idx = row * DM + h * HD + dt * 16 + l15;
      const float v = o[dt][r] * inv_l;
      if (fl) ((float*)out)[idx] = v;
      else    ((__hip_bfloat16*)out)[idx] = __float2bfloat16(v);
    }
  }
}

// ---------------------------------------------------------------------------
extern "C" void kernel_launch(void* const* d_in, const int* in_sizes, int n_in,
                              void* d_out, int out_size, void* d_ws, size_t ws_size,
                              hipStream_t stream) {
  char* ws = (char*)d_ws;
  __hip_bfloat16* wt  = (__hip_bfloat16*)(ws + 4096);          // 6 MB
  __hip_bfloat16* kqv = (__hip_bfloat16*)(ws + 4096 + 6291456);// 24 MB
  // xb lives in d_out's first 8 MB: dead until attn's epilogue overwrites all
  // of d_out, and gemm_kqv (the only xb reader) completes before attn runs.
  __hip_bfloat16* xb  = (__hip_bfloat16*)d_out;

  hipLaunchKernelGGL(prep, dim3(2048 + 768), dim3(256), 0, stream,
                     d_in[0], d_in[1], xb, wt);
  hipLaunchKernelGGL(gemm_kqv, dim3(16, 32), dim3(512), 0, stream, xb, wt, kqv);
  hipLaunchKernelGGL(attn, dim3(64, 16), dim3(256), 0, stream,
                     kqv, (const unsigned short*)d_in[0], d_out);
}